// Round 1
// baseline (32.638 us; speedup 1.0000x reference)
//
#include <hip/hip_runtime.h>
#include <hip/hip_bf16.h>

typedef __attribute__((ext_vector_type(8))) short bf16x8;
typedef __attribute__((ext_vector_type(4))) float f32x4;

#define NROW 2048      // B*L
#define DDIM 256
#define BM 64
#define BK 64
#define LSTR 72        // LDS row stride in bf16 elements (+16B pad for bank spread)

__device__ __forceinline__ unsigned short f2bf(float f) {
    unsigned u = __builtin_bit_cast(unsigned, f);
    unsigned r = (u + 0x7FFFu + ((u >> 16) & 1u)) >> 16;
    return (unsigned short)r;
}

struct MlpTask {
    const float* x;     // [2048][256]
    const float* W;     // [256][256]
    const float* b;     // [256]
    const float* g;     // [256]
    const float* beta;  // [256]
    const float* attw;  // [256] or null
    float* out;         // [2048][256]
    float* dot;         // [2048] or null
};
struct MlpArgs { MlpTask t[6]; };

// ---------------- Kernel A: 6x (GEMM + LayerNorm + ReLU) + per-row att dots ---
__global__ __launch_bounds__(256) void mlp6_kernel(MlpArgs args) {
    const int bx = blockIdx.x;
    const int mlp = bx / 32;
    const int mtile = bx % 32;
    const MlpTask tk = args.t[mlp];
    const int tid = threadIdx.x;
    const int lane = tid & 63;
    const int wave = tid >> 6;

    __shared__ unsigned short A_lds[BM * LSTR];
    __shared__ unsigned short W_lds[DDIM * LSTR];

    f32x4 acc[16];
#pragma unroll
    for (int i = 0; i < 16; ++i) acc[i] = (f32x4){0.f, 0.f, 0.f, 0.f};

    const float* xtile = tk.x + (size_t)mtile * BM * DDIM;

    const int col4 = tid & 15;   // float4 column within the 64-wide K slice
    const int r0 = tid >> 4;     // 0..15

    for (int kt = 0; kt < DDIM; kt += BK) {
        // stage A tile: 64 rows x 64 cols (fp32 -> bf16)
#pragma unroll
        for (int i = 0; i < 4; ++i) {
            int r = r0 + i * 16;
            f32x4 v = *(const f32x4*)(xtile + r * DDIM + kt + col4 * 4);
            ushort4 w4 = { f2bf(v.x), f2bf(v.y), f2bf(v.z), f2bf(v.w) };
            *(ushort4*)&A_lds[r * LSTR + col4 * 4] = w4;
        }
        // stage W slice: 256 rows x 64 cols
#pragma unroll
        for (int i = 0; i < 16; ++i) {
            int r = r0 + i * 16;
            f32x4 v = *(const f32x4*)(tk.W + r * DDIM + kt + col4 * 4);
            ushort4 w4 = { f2bf(v.x), f2bf(v.y), f2bf(v.z), f2bf(v.w) };
            *(ushort4*)&W_lds[r * LSTR + col4 * 4] = w4;
        }
        __syncthreads();

        const int m0 = wave * 16;
        const int arow = m0 + (lane & 15);
        const int koff = (lane >> 4) * 8;
#pragma unroll
        for (int kk = 0; kk < BK; kk += 32) {
            bf16x8 a = *(const bf16x8*)&A_lds[arow * LSTR + kk + koff];
#pragma unroll
            for (int nt = 0; nt < 16; ++nt) {
                bf16x8 b = *(const bf16x8*)&W_lds[(nt * 16 + (lane & 15)) * LSTR + kk + koff];
                acc[nt] = __builtin_amdgcn_mfma_f32_16x16x32_bf16(a, b, acc[nt], 0, 0, 0);
            }
        }
        __syncthreads();
    }

    // ------- epilogue: bias + LN + ReLU + store + partial attention dot -------
    const int m0 = wave * 16;
    const int cq = lane & 15;   // column within 16-wide N tile
    const int rq = lane >> 4;   // row quarter

    float bcol[16], gcol[16], betacol[16], awcol[16];
#pragma unroll
    for (int nt = 0; nt < 16; ++nt) {
        int c = nt * 16 + cq;
        bcol[nt] = tk.b[c];
        gcol[nt] = tk.g[c];
        betacol[nt] = tk.beta[c];
        awcol[nt] = tk.attw ? tk.attw[c] : 0.f;
    }

#pragma unroll
    for (int r = 0; r < 4; ++r) {
        float v[16];
        float sum = 0.f, sq = 0.f;
#pragma unroll
        for (int nt = 0; nt < 16; ++nt) {
            float t = acc[nt][r] + bcol[nt];
            v[nt] = t;
            sum += t;
            sq += t * t;
        }
#pragma unroll
        for (int m = 1; m < 16; m <<= 1) {
            sum += __shfl_xor(sum, m, 64);
            sq  += __shfl_xor(sq, m, 64);
        }
        float mean = sum * (1.f / 256.f);
        float var = sq * (1.f / 256.f) - mean * mean;
        float rstd = rsqrtf(var + 1e-5f);

        int grow = mtile * BM + m0 + rq * 4 + r;
        float* orow = tk.out + (size_t)grow * DDIM;
        float pd = 0.f;
#pragma unroll
        for (int nt = 0; nt < 16; ++nt) {
            float o = (v[nt] - mean) * rstd * gcol[nt] + betacol[nt];
            o = fmaxf(o, 0.f);
            orow[nt * 16 + cq] = o;
            pd += o * awcol[nt];
        }
        if (tk.dot) {
#pragma unroll
            for (int m = 1; m < 16; m <<= 1) pd += __shfl_xor(pd, m, 64);
            if (cq == 0) tk.dot[grow] = pd;
        }
    }
}

// ---------------- Kernel B: interaction elementwise combine ------------------
__device__ __forceinline__ float sigm(float x) {
    return 1.f / (1.f + __expf(-x));
}

__global__ __launch_bounds__(256) void interact_kernel(
    const float* __restrict__ cg, const float* __restrict__ cp,
    const float* __restrict__ sg, const float* __restrict__ sp,
    const float* __restrict__ dots,   // [4][2048]
    const float* __restrict__ c_agb, const float* __restrict__ c_apb,
    const float* __restrict__ s_agb, const float* __restrict__ s_apb,
    float* __restrict__ out_common, float* __restrict__ out_synergy)
{
    int gid = blockIdx.x * 256 + threadIdx.x;   // one float4 each, 131072 total
    int row = gid >> 6;                          // 64 float4 per row

    float cagb = *c_agb, capb = *c_apb, sagb = *s_agb, sapb = *s_apb;
    float d_cg_apw = dots[0 * NROW + row];  // dot(c_g_align, c_apw)
    float d_cp_agw = dots[1 * NROW + row];  // dot(c_p_align, c_agw)
    float d_sg_apw = dots[2 * NROW + row];
    float d_sp_agw = dots[3 * NROW + row];

    f32x4 vcg = ((const f32x4*)cg)[gid];
    f32x4 vcp = ((const f32x4*)cp)[gid];
    f32x4 vsg = ((const f32x4*)sg)[gid];
    f32x4 vsp = ((const f32x4*)sp)[gid];

    f32x4 oc, os;
#pragma unroll
    for (int i = 0; i < 4; ++i) {
        // common = p_align*sigmoid(p_align*dot(g_align,apw)+apb)
        //        + g_align*sigmoid(g_align*dot(p_align,agw)+agb)
        oc[i] = vcp[i] * sigm(vcp[i] * d_cg_apw + capb)
              + vcg[i] * sigm(vcg[i] * d_cp_agw + cagb);
        os[i] = vsp[i] * sigm(vsp[i] * d_sg_apw + sapb)
              + vsg[i] * sigm(vsg[i] * d_sp_agw + sagb);
    }
    ((f32x4*)out_common)[gid] = oc;
    ((f32x4*)out_synergy)[gid] = os;
}

// -----------------------------------------------------------------------------
extern "C" void kernel_launch(void* const* d_in, const int* in_sizes, int n_in,
                              void* d_out, int out_size, void* d_ws, size_t ws_size,
                              hipStream_t stream) {
    const float* gfeat = (const float*)d_in[0];
    const float* pfeat = (const float*)d_in[1];

    float* out = (float*)d_out;
    float* wsf = (float*)d_ws;
    const size_t S = (size_t)NROW * DDIM;   // 524288

    float* out_common  = out + 0 * S;
    float* out_synergy = out + 1 * S;
    float* out_gspec   = out + 2 * S;
    float* out_pspec   = out + 3 * S;

    float* ws_cg = wsf + 0 * S;
    float* ws_cp = wsf + 1 * S;
    float* ws_sg = wsf + 2 * S;
    float* ws_sp = wsf + 3 * S;
    float* ws_dots = wsf + 4 * S;           // [4][2048]

    MlpArgs args;
    // 0: g_spec = mlp(gfeat, gs_*)
    args.t[0] = { gfeat, (const float*)d_in[2], (const float*)d_in[3],
                  (const float*)d_in[4], (const float*)d_in[5],
                  nullptr, out_gspec, nullptr };
    // 1: p_spec = mlp(pfeat, ps_*)
    args.t[1] = { pfeat, (const float*)d_in[6], (const float*)d_in[7],
                  (const float*)d_in[8], (const float*)d_in[9],
                  nullptr, out_pspec, nullptr };
    // 2: c_g_align = mlp(pfeat, c_g_*); dot with c_apw -> slot 0
    args.t[2] = { pfeat, (const float*)d_in[10], (const float*)d_in[11],
                  (const float*)d_in[12], (const float*)d_in[13],
                  (const float*)d_in[20], ws_cg, ws_dots + 0 * NROW };
    // 3: c_p_align = mlp(gfeat, c_p_*); dot with c_agw -> slot 1
    args.t[3] = { gfeat, (const float*)d_in[14], (const float*)d_in[15],
                  (const float*)d_in[16], (const float*)d_in[17],
                  (const float*)d_in[18], ws_cp, ws_dots + 1 * NROW };
    // 4: s_g_align = mlp(pfeat, s_g_*); dot with s_apw -> slot 2
    args.t[4] = { pfeat, (const float*)d_in[22], (const float*)d_in[23],
                  (const float*)d_in[24], (const float*)d_in[25],
                  (const float*)d_in[32], ws_sg, ws_dots + 2 * NROW };
    // 5: s_p_align = mlp(gfeat, s_p_*); dot with s_agw -> slot 3
    args.t[5] = { gfeat, (const float*)d_in[26], (const float*)d_in[27],
                  (const float*)d_in[28], (const float*)d_in[29],
                  (const float*)d_in[30], ws_sp, ws_dots + 3 * NROW };

    hipLaunchKernelGGL(mlp6_kernel, dim3(192), dim3(256), 0, stream, args);

    hipLaunchKernelGGL(interact_kernel, dim3(512), dim3(256), 0, stream,
                       ws_cg, ws_cp, ws_sg, ws_sp, ws_dots,
                       (const float*)d_in[19], (const float*)d_in[21],
                       (const float*)d_in[31], (const float*)d_in[33],
                       out_common, out_synergy);
}